// Round 1
// baseline (478.551 us; speedup 1.0000x reference)
//
#include <hip/hip_runtime.h>
#include <hip/hip_fp16.h>

#define NB 2048
#define NC 8
#define NT 1024
#define EPS 1e-5f
#define SLOPE (1.0f/128.0f)
#define NELEM (2048.0f*1024.0f)

// ---- ws layout (float indices unless noted) ----
// [0,1024)            bn1 partials: 64 slots x 16
// [1024,9216)         bn2 partials: 256 slots x 32
// [9216,9600)         params
// byte 65536          f_ws  fp16 [T][B][8]   (32 MB)
// byte 65536+32MB     pre_ws fp16 [B][T][12] (48 MB)
#define PAR_OFF 9216
#define P_S   0
#define P_O   8
#define P_W1F 16
#define P_B1F 208
#define P_W3X 232
#define P_B3F 320
#define P_AL  336
#define P_BE  352
#define FWS_BYTE 65536
#define PWS_BYTE (65536 + 2048*1024*8*2)

__device__ __forceinline__ float leaky(float z){ return z >= 0.f ? z : z*SLOPE; }
__device__ __forceinline__ unsigned short f2h(float v){ return __half_as_ushort(__float2half(v)); }
__device__ __forceinline__ float h2f(unsigned short u){ return __half2float(__ushort_as_half(u)); }

// ---------------- K1: BN1 stats (sum, sumsq per channel) ----------------
__global__ __launch_bounds__(256) void k1_bn1(const float* __restrict__ x, float* __restrict__ ws)
{
    const int b = blockIdx.x, tid = threadIdx.x;
    const float* xb = x + (size_t)b*(NC*NT);
    float s[8], s2[8];
#pragma unroll
    for(int c=0;c<8;c++){
        float4 v = ((const float4*)(xb + c*NT))[tid];           // coalesced, covers all T
        s[c]  = v.x+v.y+v.z+v.w;
        s2[c] = v.x*v.x+v.y*v.y+v.z*v.z+v.w*v.w;
    }
#pragma unroll
    for(int c=0;c<8;c++){
#pragma unroll
        for(int m=32;m>=1;m>>=1){ s[c]+=__shfl_xor(s[c],m,64); s2[c]+=__shfl_xor(s2[c],m,64); }
    }
    __shared__ float red[4][16];
    const int wave = tid>>6, lane = tid&63;
    if(lane==0){
#pragma unroll
        for(int c=0;c<8;c++){ red[wave][c]=s[c]; red[wave][8+c]=s2[c]; }
    }
    __syncthreads();
    if(tid<16){
        float tot = red[0][tid]+red[1][tid]+red[2][tid]+red[3][tid];
        atomicAdd(&ws[(b&63)*16 + tid], tot);   // 64 slots -> low contention
    }
}

// ---------------- K2: finalize BN1, fold weights ----------------
__global__ __launch_bounds__(256) void k2_fold(const float* __restrict__ g1, const float* __restrict__ bb1,
    const float* __restrict__ w1, const float* __restrict__ b1,
    const float* __restrict__ w3, const float* __restrict__ b3, float* __restrict__ ws)
{
    float* par = ws + PAR_OFF;
    __shared__ float st[16];
    __shared__ float sc[8], oc[8];
    const int tid = threadIdx.x;
    if(tid<16){
        float s=0.f;
        for(int i=0;i<64;i++) s += ws[i*16+tid];
        st[tid]=s;
    }
    __syncthreads();
    if(tid<8){
        const float inv = 1.0f/NELEM;
        float m  = st[tid]*inv;
        float v  = st[8+tid]*inv - m*m;
        float s_ = g1[tid]*rsqrtf(v+EPS);
        float o_ = bb1[tid] - m*s_;
        sc[tid]=s_; oc[tid]=o_;
        par[P_S+tid]=s_; par[P_O+tid]=o_;
    }
    __syncthreads();
    if(tid<192){ int o=tid>>3, c=tid&7; par[P_W1F+tid] = w1[o*8+c]*sc[c]; }
    if(tid<88) { int o=tid>>3, c=tid&7; par[P_W3X+tid] = w3[o*48+c] + w3[o*48+8+c]*sc[c]; }
    if(tid<24){ float a=b1[tid]; for(int c2=0;c2<8;c2++) a += w1[tid*8+c2]*oc[c2]; par[P_B1F+tid]=a; }
    if(tid<11){ float a=b3[tid]; for(int c2=0;c2<8;c2++) a += w3[tid*48+8+c2]*oc[c2]; par[P_B3F+tid]=a; }
}

// ---------------- K3: reservoir, chunked over T with warm-up ----------------
// block = 1 wave = 64 consecutive b, fixed chunk k (uniform loop bounds per wave).
// chunk L=32 steps, warm-up W=48 from f=0 (contraction: ||4A||_2 < 1, decay ~0.4^k).
__global__ __launch_bounds__(64) void k3_res(const float* __restrict__ x, const float* __restrict__ A,
                                             const float* __restrict__ ws, unsigned short* __restrict__ fws)
{
    const float* par = ws + PAR_OFF;
    const int k  = blockIdx.x & 31;
    const int b  = (blockIdx.x >> 5)*64 + threadIdx.x;
    const int t0 = k*32;
    const int tw = (t0 >= 48) ? (t0-48) : 0;   // multiple of 16 -> float4-aligned
    const int tend = t0 + 32;

    float Ar[64];
#pragma unroll
    for(int z=0; z<64; z++) Ar[z] = 4.0f*A[z];            // fold the 4x into A
    float sc4[8], oc4[8];
#pragma unroll
    for(int i=0;i<8;i++){ sc4[i] = 4.0f*par[P_S+i]; oc4[i] = 4.0f*par[P_O+i]; }

    const float* xb = x + (size_t)b*(NC*NT);
    float f[8];
#pragma unroll
    for(int i=0;i<8;i++) f[i]=0.f;

    float4 xv[8];
#pragma unroll
    for(int c=0;c<8;c++) xv[c] = *(const float4*)(xb + c*NT + tw);

    for(int t4=tw; t4<tend; t4+=4){
        float4 xn[8];
        if(t4+4 < tend){                                  // software prefetch next group
#pragma unroll
            for(int c=0;c<8;c++) xn[c] = *(const float4*)(xb + c*NT + t4+4);
        }
#pragma unroll
        for(int s=0;s<4;s++){
            float nf[8];
#pragma unroll
            for(int i=0;i<8;i++){
                float xs = (s==0)?xv[i].x:(s==1)?xv[i].y:(s==2)?xv[i].z:xv[i].w;
                float acc = sc4[i]*xs + oc4[i];           // 4*(s*x+o): BN1 folded, 4x folded
#pragma unroll
                for(int j=0;j<8;j++) acc += Ar[i*8+j]*f[j];
                nf[i] = fminf(fmaxf(acc,-1.f),1.f);       // v_med3
            }
#pragma unroll
            for(int i=0;i<8;i++) f[i]=nf[i];
            const int t = t4+s;
            if(t >= t0){                                   // uniform branch (k uniform per wave)
                union { unsigned short us[8]; float4 v; } u;
#pragma unroll
                for(int i=0;i<8;i++) u.us[i] = f2h(f[i]);
                *(float4*)(fws + ((size_t)t*NB + b)*8) = u.v;   // lanes on b: coalesced 1KB
            }
        }
#pragma unroll
        for(int c=0;c<8;c++) xv[c]=xn[c];
    }
}

// ---------------- K4: fused FF branch + pre + BN2 partial sums ----------------
// block = (b, half of T), lanes on t. 2 positions/thread, layer-major (weights reused locally).
__global__ __launch_bounds__(256) void k4_ff(
    const float* __restrict__ x, const float* __restrict__ w2g, const float* __restrict__ b2g,
    const float* __restrict__ w3g, float* __restrict__ ws,
    const unsigned short* __restrict__ fws, unsigned short* __restrict__ pws)
{
    const float* par = ws + PAR_OFF;
    const int tid = threadIdx.x;
    const int b = blockIdx.x >> 1;
    const int tbase = (blockIdx.x & 1)*512 + tid;
    const float* xb = x + (size_t)b*(NC*NT);

    float xr[2][8], fr[2][8], lr[2][8];
#pragma unroll
    for(int g=0; g<2; g++){
        const int t = tbase + g*256;
#pragma unroll
        for(int c=0;c<8;c++) xr[g][c] = xb[c*NT + t];      // coalesced per channel
        union { unsigned short us[8]; float4 v; } uf;
        uf.v = *(const float4*)(fws + ((size_t)t*NB + b)*8);
#pragma unroll
        for(int i=0;i<8;i++){ float fv=h2f(uf.us[i]); fr[g][i]=fv; lr[g][i]=leaky(fv); }
    }
    // pre partial: b3f + w3x'*x (x+bw folded) + w3*f + w3*leaky(f)  -> xr can die after layer 1
    float pr[2][11];
#pragma unroll
    for(int o=0;o<11;o++){
        float z0 = par[P_B3F+o], z1 = z0;
#pragma unroll
        for(int c=0;c<8;c++){ float w = par[P_W3X+o*8+c]; z0 += w*xr[0][c]; z1 += w*xr[1][c]; }
#pragma unroll
        for(int i=0;i<8;i++){ float w = w3g[o*48+32+i]; z0 += w*fr[0][i]; z1 += w*fr[1][i]; }
#pragma unroll
        for(int i=0;i<8;i++){ float w = w3g[o*48+40+i]; z0 += w*lr[0][i]; z1 += w*lr[1][i]; }
        pr[0][o]=z0; pr[1][o]=z1;
    }
    float h[2][24];
#pragma unroll
    for(int o=0;o<24;o++){
        float z0 = par[P_B1F+o], z1 = z0;
#pragma unroll
        for(int c=0;c<8;c++){ float w = par[P_W1F+o*8+c]; z0 += w*xr[0][c]; z1 += w*xr[1][c]; }
        h[0][o]=leaky(z0); h[1][o]=leaky(z1);
    }
    float ff[2][16];
#pragma unroll
    for(int o=0;o<16;o++){
        float z0 = b2g[o], z1 = z0;
#pragma unroll
        for(int c=0;c<24;c++){ float w = w2g[o*24+c]; z0 += w*h[0][c]; z1 += w*h[1][c]; }
        ff[0][o]=leaky(z0); ff[1][o]=leaky(z1);
    }
#pragma unroll
    for(int o=0;o<11;o++){
        float z0 = pr[0][o], z1 = pr[1][o];
#pragma unroll
        for(int c=0;c<16;c++){ float w = w3g[o*48+16+c]; z0 += w*ff[0][c]; z1 += w*ff[1][c]; }
        pr[0][o]=z0; pr[1][o]=z1;
    }
    // store pre (fp16, 12 halves incl pad; 8B stores keep alignment at 24B stride)
#pragma unroll
    for(int g=0; g<2; g++){
        const int t = tbase + g*256;
        union { unsigned short us[12]; uint2 u[3]; } up;
#pragma unroll
        for(int o=0;o<11;o++) up.us[o] = f2h(pr[g][o]);
        up.us[11] = 0;
        uint2* dst = (uint2*)(pws + ((size_t)b*NT + t)*12);
        dst[0]=up.u[0]; dst[1]=up.u[1]; dst[2]=up.u[2];
    }
    // BN2 partial sums
    float s1[11], s2[11];
#pragma unroll
    for(int o=0;o<11;o++){ s1[o]=pr[0][o]+pr[1][o]; s2[o]=pr[0][o]*pr[0][o]+pr[1][o]*pr[1][o]; }
#pragma unroll
    for(int o=0;o<11;o++){
#pragma unroll
        for(int m=32;m>=1;m>>=1){ s1[o]+=__shfl_xor(s1[o],m,64); s2[o]+=__shfl_xor(s2[o],m,64); }
    }
    __shared__ float red[4][22];
    const int wave=tid>>6, lane=tid&63;
    if(lane==0){
#pragma unroll
        for(int o=0;o<11;o++){ red[wave][o]=s1[o]; red[wave][11+o]=s2[o]; }
    }
    __syncthreads();
    if(tid<22){
        float tot = red[0][tid]+red[1][tid]+red[2][tid]+red[3][tid];
        atomicAdd(&ws[1024 + (blockIdx.x & 255)*32 + tid], tot);  // 256 slots
    }
}

// ---------------- K5: finalize BN2 ----------------
__global__ __launch_bounds__(64) void k5_fin(const float* __restrict__ g2, const float* __restrict__ bb2,
                                             float* __restrict__ ws)
{
    __shared__ float st[22];
    const int tid = threadIdx.x;
    if(tid<22){
        float s=0.f;
        for(int i=0;i<256;i++) s += ws[1024 + i*32 + tid];
        st[tid]=s;
    }
    __syncthreads();
    if(tid<11){
        const float inv = 1.0f/NELEM;
        float m = st[tid]*inv;
        float v = st[11+tid]*inv - m*m;
        float a = g2[tid]*rsqrtf(v+EPS);
        ws[PAR_OFF+P_AL+tid] = a;
        ws[PAR_OFF+P_BE+tid] = bb2[tid] - m*a;
    }
}

// ---------------- K6: BN2 apply + leaky + mean over t ----------------
__global__ __launch_bounds__(256) void k6_out(const float* __restrict__ ws, const unsigned short* __restrict__ pws,
                                              float* __restrict__ out)
{
    const float* par = ws + PAR_OFF;
    float al[11], be[11];
#pragma unroll
    for(int o=0;o<11;o++){ al[o]=par[P_AL+o]; be[o]=par[P_BE+o]; }
    const int b = blockIdx.x, tid = threadIdx.x;
    float acc[11];
#pragma unroll
    for(int o=0;o<11;o++) acc[o]=0.f;
#pragma unroll
    for(int g=0; g<4; g++){
        const int t = g*256 + tid;
        const uint2* sp = (const uint2*)(pws + ((size_t)b*NT + t)*12);
        union { unsigned short us[12]; uint2 u[3]; } up;
        up.u[0]=sp[0]; up.u[1]=sp[1]; up.u[2]=sp[2];
#pragma unroll
        for(int o=0;o<11;o++){
            float z = al[o]*h2f(up.us[o]) + be[o];
            acc[o] += leaky(z);
        }
    }
#pragma unroll
    for(int o=0;o<11;o++){
#pragma unroll
        for(int m=32;m>=1;m>>=1) acc[o]+=__shfl_xor(acc[o],m,64);
    }
    __shared__ float red[4][11];
    const int wave=tid>>6, lane=tid&63;
    if(lane==0){
#pragma unroll
        for(int o=0;o<11;o++) red[wave][o]=acc[o];
    }
    __syncthreads();
    if(tid<11){
        out[(size_t)b*11+tid] = (red[0][tid]+red[1][tid]+red[2][tid]+red[3][tid]) * (1.0f/NT);
    }
}

extern "C" void kernel_launch(void* const* d_in, const int* in_sizes, int n_in,
                              void* d_out, int out_size, void* d_ws, size_t ws_size,
                              hipStream_t stream)
{
    const float* x   = (const float*)d_in[0];
    const float* A   = (const float*)d_in[1];
    const float* g1  = (const float*)d_in[2];
    const float* bb1 = (const float*)d_in[3];
    const float* w1  = (const float*)d_in[4];
    const float* b1  = (const float*)d_in[5];
    const float* w2  = (const float*)d_in[6];
    const float* b2  = (const float*)d_in[7];
    const float* w3  = (const float*)d_in[8];
    const float* b3  = (const float*)d_in[9];
    const float* g2  = (const float*)d_in[10];
    const float* bb2 = (const float*)d_in[11];
    float* out = (float*)d_out;
    float* ws  = (float*)d_ws;
    unsigned short* fws = (unsigned short*)((char*)d_ws + FWS_BYTE);
    unsigned short* pws = (unsigned short*)((char*)d_ws + PWS_BYTE);

    hipMemsetAsync(d_ws, 0, 38400, stream);                 // zero reduction slots + params
    k1_bn1<<<NB, 256, 0, stream>>>(x, ws);
    k2_fold<<<1, 256, 0, stream>>>(g1, bb1, w1, b1, w3, b3, ws);
    k3_res<<<1024, 64, 0, stream>>>(x, A, ws, fws);
    k4_ff<<<NB*2, 256, 0, stream>>>(x, w2, b2, w3, ws, fws, pws);
    k5_fin<<<1, 64, 0, stream>>>(g2, bb2, ws);
    k6_out<<<NB, 256, 0, stream>>>(ws, pws, out);
}

// Round 2
// 474.065 us; speedup vs baseline: 1.0095x; 1.0095x over previous
//
#include <hip/hip_runtime.h>
#include <hip/hip_fp16.h>

#define NB 2048
#define NC 8
#define NT 1024
#define EPS 1e-5f
#define SLOPE (1.0f/128.0f)
#define NELEM (2048.0f*1024.0f)

// ---- ws layout ----
// floats [0,1024)      : bn1 partials, 64 slots x 16
// floats [1024,9216)   : bn2 partials, 256 slots x 32
// floats [9216,9600)   : folded params
// byte 65536           : xT  fp16 [T][B][8]   (32 MiB)   (dead after k34 -> reused as k6 partials)
// byte 65536+32MiB     : pre fp16 [B-major? no: [t][b][12]] (48 MiB)
#define PAR_OFF 9216
#define P_S   0
#define P_O   8
#define P_W1F 16
#define P_B1F 208
#define P_W3X 232
#define P_B3F 320
#define P_AL  336
#define P_BE  352
#define XT_BYTE  65536
#define PWS_BYTE (65536 + 2048*1024*8*2)

__device__ __forceinline__ float leaky(float z){ return z >= 0.f ? z : z*SLOPE; }
__device__ __forceinline__ unsigned short f2h(float v){ return __half_as_ushort(__float2half(v)); }
__device__ __forceinline__ float h2f(unsigned short u){ return __half2float(__ushort_as_half(u)); }

// ---------------- K0: BN1 stats + transpose x -> xT[t][b][8] fp16 ----------------
// grid: 128 bgroups(16 b) x 16 tgroups(64 t) = 2048 blocks, 256 thr.
// read coalesced (lanes on t), LDS transpose (t-row stride 134 halves: 2-way max), write coalesced.
__global__ __launch_bounds__(256) void k0_tr(const float* __restrict__ x,
                                             unsigned short* __restrict__ xT,
                                             float* __restrict__ ws)
{
    __shared__ unsigned short tile[64*134];
    __shared__ float sred[4][4][2];
    const int tid = threadIdx.x;
    const int bg = blockIdx.x >> 4;
    const int tg = blockIdx.x & 15;
    const int b0 = bg*16, t0 = tg*64;
    float s = 0.f, s2 = 0.f;
#pragma unroll
    for(int r=0;r<8;r++){
        const int flat4 = r*256 + tid;
        const int row = flat4 >> 4;          // 0..127 = b*8+c
        const int t4  = flat4 & 15;
        const int b = row >> 3, c = row & 7;
        float4 v = *(const float4*)(x + (size_t)(b0+b)*8192 + c*1024 + t0 + t4*4);
        s  += v.x+v.y+v.z+v.w;
        s2 += v.x*v.x+v.y*v.y+v.z*v.z+v.w*v.w;
        const int base = b*8 + c;
        tile[(t4*4+0)*134 + base] = f2h(v.x);
        tile[(t4*4+1)*134 + base] = f2h(v.y);
        tile[(t4*4+2)*134 + base] = f2h(v.z);
        tile[(t4*4+3)*134 + base] = f2h(v.w);
    }
    // per-thread c is constant: c = (tid>>4)&7; reduce within 16-lane groups
#pragma unroll
    for(int m=8;m>=1;m>>=1){ s += __shfl_xor(s,m,64); s2 += __shfl_xor(s2,m,64); }
    const int lane = tid & 63, wave = tid >> 6;
    if((lane & 15) == 0){ sred[wave][lane>>4][0] = s; sred[wave][lane>>4][1] = s2; }
    __syncthreads();
    if(tid < 16){
        const int c = tid & 7, which = tid >> 3;
        const int w0 = (c < 4) ? 0 : 1, g = c & 3;
        const float v = sred[w0][g][which] + sred[w0+2][g][which];
        atomicAdd(&ws[(blockIdx.x & 63)*16 + which*8 + c], v);
    }
    // write xT: per t, 128 contiguous halves (16 b x 8 c)
#pragma unroll
    for(int r=0;r<8;r++){
        const int q = r*256 + tid;
        const int t = q >> 5, inner = q & 31;
        const unsigned int lo = *(const unsigned int*)&tile[t*134 + inner*4];
        const unsigned int hi = *(const unsigned int*)&tile[t*134 + inner*4 + 2];
        *(uint2*)(xT + ((size_t)(t0+t)*NB + b0)*8 + inner*4) = make_uint2(lo, hi);
    }
}

// ---------------- K2: finalize BN1, fold weights ----------------
__global__ __launch_bounds__(256) void k2_fold(const float* __restrict__ g1, const float* __restrict__ bb1,
    const float* __restrict__ w1, const float* __restrict__ b1,
    const float* __restrict__ w3, const float* __restrict__ b3, float* __restrict__ ws)
{
    float* par = ws + PAR_OFF;
    __shared__ float st[16];
    __shared__ float sc[8], oc[8];
    const int tid = threadIdx.x;
    if(tid<16){
        float s=0.f;
        for(int i=0;i<64;i++) s += ws[i*16+tid];
        st[tid]=s;
    }
    __syncthreads();
    if(tid<8){
        const float inv = 1.0f/NELEM;
        float m  = st[tid]*inv;
        float v  = st[8+tid]*inv - m*m;
        float s_ = g1[tid]*rsqrtf(v+EPS);
        float o_ = bb1[tid] - m*s_;
        sc[tid]=s_; oc[tid]=o_;
        par[P_S+tid]=s_; par[P_O+tid]=o_;
    }
    __syncthreads();
    if(tid<192){ int o=tid>>3, c=tid&7; par[P_W1F+tid] = w1[o*8+c]*sc[c]; }
    if(tid<88) { int o=tid>>3, c=tid&7; par[P_W3X+tid] = w3[o*48+c] + w3[o*48+8+c]*sc[c]; }
    if(tid<24){ float a=b1[tid]; for(int c2=0;c2<8;c2++) a += w1[tid*8+c2]*oc[c2]; par[P_B1F+tid]=a; }
    if(tid<11){ float a=b3[tid]; for(int c2=0;c2<8;c2++) a += w3[tid*48+8+c2]*oc[c2]; par[P_B3F+tid]=a; }
}

// ---------------- K34: fused reservoir + FF + pre + BN2 partials ----------------
// grid: 8 bgroups(256 b) x 64 tgroups(16 t) = 512 blocks x 256 thr. Lanes on b: all
// xT/pws accesses coalesced. Each thread: 48-step warm-up (contraction ||4A||~0.8,
// 0.8^48 ~ 2e-5) then 16 body steps, FF fused per body step. No f buffer.
__global__ __launch_bounds__(256) void k34(
    const unsigned short* __restrict__ xT, const float* __restrict__ A,
    const float* __restrict__ w2g, const float* __restrict__ b2g, const float* __restrict__ w3g,
    float* __restrict__ ws, unsigned short* __restrict__ pws)
{
    const float* par = ws + PAR_OFF;
    const int tid = threadIdx.x;
    const int b  = (blockIdx.x >> 6)*256 + tid;
    const int tg = blockIdx.x & 63;
    const int t0 = tg*16;
    const int tw = (t0 >= 48) ? (t0 - 48) : 0;
    const int tend = t0 + 16;

    float A4[64];
#pragma unroll
    for(int z=0;z<64;z++) A4[z] = 4.0f*A[z];          // uniform -> SGPRs
    float sc4[8], oc4[8];
#pragma unroll
    for(int i=0;i<8;i++){ sc4[i] = 4.f*par[P_S+i]; oc4[i] = 4.f*par[P_O+i]; }

    float f[8];
#pragma unroll
    for(int i=0;i<8;i++) f[i]=0.f;
    float s1[11], s2[11];
#pragma unroll
    for(int o=0;o<11;o++){ s1[o]=0.f; s2[o]=0.f; }

    float4 q[4];                                       // prefetch queue, depth 4
#pragma unroll
    for(int i=0;i<4;i++) q[i] = *(const float4*)(xT + ((size_t)(tw+i)*NB + b)*8);

    for(int t=tw; t<tend; t++){
        union { float4 v; unsigned short us[8]; } ux; ux.v = q[0];
        q[0]=q[1]; q[1]=q[2]; q[2]=q[3];
        if(t+4 < tend) q[3] = *(const float4*)(xT + ((size_t)(t+4)*NB + b)*8);
        float xf[8];
#pragma unroll
        for(int i=0;i<8;i++) xf[i] = h2f(ux.us[i]);
        float nf[8];
#pragma unroll
        for(int i=0;i<8;i++){
            float acc = sc4[i]*xf[i] + oc4[i];         // 4*(s*x+o)
#pragma unroll
            for(int j=0;j<8;j++) acc += A4[i*8+j]*f[j];
            nf[i] = fminf(fmaxf(acc,-1.f),1.f);        // v_med3
        }
#pragma unroll
        for(int i=0;i<8;i++) f[i]=nf[i];
        if(t >= t0){                                    // uniform branch
            float lf[8];
#pragma unroll
            for(int i=0;i<8;i++) lf[i] = leaky(f[i]);
            float pr[11];
#pragma unroll
            for(int o=0;o<11;o++){
                float z = par[P_B3F+o];
#pragma unroll
                for(int c=0;c<8;c++) z += par[P_W3X+o*8+c]*xf[c];   // x + bw folded
#pragma unroll
                for(int i=0;i<8;i++) z += w3g[o*48+32+i]*f[i];
#pragma unroll
                for(int i=0;i<8;i++) z += w3g[o*48+40+i]*lf[i];
                pr[o]=z;
            }
            float h[24];
#pragma unroll
            for(int o=0;o<24;o++){
                float z = par[P_B1F+o];
#pragma unroll
                for(int c=0;c<8;c++) z += par[P_W1F+o*8+c]*xf[c];
                h[o]=leaky(z);
            }
            float ff[16];
#pragma unroll
            for(int o=0;o<16;o++){
                float z = b2g[o];
#pragma unroll
                for(int c=0;c<24;c++) z += w2g[o*24+c]*h[c];
                ff[o]=leaky(z);
            }
#pragma unroll
            for(int o=0;o<11;o++){
                float z = pr[o];
#pragma unroll
                for(int c=0;c<16;c++) z += w3g[o*48+16+c]*ff[c];
                pr[o]=z;
                s1[o]+=z; s2[o]+=z*z;
            }
            union { unsigned short us[12]; uint2 u[3]; } up;
#pragma unroll
            for(int o=0;o<11;o++) up.us[o] = f2h(pr[o]);
            up.us[11] = 0;
            uint2* dst = (uint2*)(pws + ((size_t)t*NB + b)*12);   // lanes on b: contiguous
            dst[0]=up.u[0]; dst[1]=up.u[1]; dst[2]=up.u[2];
        }
    }
    // BN2 partial reduction
#pragma unroll
    for(int o=0;o<11;o++){
#pragma unroll
        for(int m=32;m>=1;m>>=1){ s1[o]+=__shfl_xor(s1[o],m,64); s2[o]+=__shfl_xor(s2[o],m,64); }
    }
    __shared__ float red[4][22];
    const int wave=tid>>6, lane=tid&63;
    if(lane==0){
#pragma unroll
        for(int o=0;o<11;o++){ red[wave][o]=s1[o]; red[wave][11+o]=s2[o]; }
    }
    __syncthreads();
    if(tid<22){
        float tot = red[0][tid]+red[1][tid]+red[2][tid]+red[3][tid];
        atomicAdd(&ws[1024 + (blockIdx.x & 255)*32 + tid], tot);
    }
}

// ---------------- K5: finalize BN2 ----------------
__global__ __launch_bounds__(64) void k5_fin(const float* __restrict__ g2, const float* __restrict__ bb2,
                                             float* __restrict__ ws)
{
    __shared__ float st[22];
    const int tid = threadIdx.x;
    if(tid<22){
        float s=0.f;
        for(int i=0;i<256;i++) s += ws[1024 + i*32 + tid];
        st[tid]=s;
    }
    __syncthreads();
    if(tid<11){
        const float inv = 1.0f/NELEM;
        float m = st[tid]*inv;
        float v = st[11+tid]*inv - m*m;
        float a = g2[tid]*rsqrtf(v+EPS);
        ws[PAR_OFF+P_AL+tid] = a;
        ws[PAR_OFF+P_BE+tid] = bb2[tid] - m*a;
    }
}

// ---------------- K6a: BN2 apply + leaky + partial t-sums (no atomics) ----------------
// grid: 8 bgroups(256 b) x 32 tgroups(32 t) = 256 blocks. partial[tg][b][11] into dead xT region.
__global__ __launch_bounds__(256) void k6_acc(const float* __restrict__ ws,
                                              const unsigned short* __restrict__ pws,
                                              float* __restrict__ partial)
{
    const float* par = ws + PAR_OFF;
    float al[11], be[11];
#pragma unroll
    for(int o=0;o<11;o++){ al[o]=par[P_AL+o]; be[o]=par[P_BE+o]; }
    const int tid = threadIdx.x;
    const int b  = (blockIdx.x >> 5)*256 + tid;
    const int tg = blockIdx.x & 31;
    float acc[11];
#pragma unroll
    for(int o=0;o<11;o++) acc[o]=0.f;
    for(int i=0;i<32;i++){
        const int t = tg*32 + i;
        const uint2* sp = (const uint2*)(pws + ((size_t)t*NB + b)*12);
        union { unsigned short us[12]; uint2 u[3]; } up;
        up.u[0]=sp[0]; up.u[1]=sp[1]; up.u[2]=sp[2];
#pragma unroll
        for(int o=0;o<11;o++) acc[o] += leaky(al[o]*h2f(up.us[o]) + be[o]);
    }
    float* dst = partial + ((size_t)tg*NB + b)*11;
#pragma unroll
    for(int o=0;o<11;o++) dst[o] = acc[o];
}

// ---------------- K6b: final mean ----------------
__global__ __launch_bounds__(256) void k6_out(const float* __restrict__ partial, float* __restrict__ out)
{
    const int i = blockIdx.x*256 + threadIdx.x;   // 88*256 = 22528 = 2048*11 exactly
    float s = 0.f;
    for(int tg=0; tg<32; tg++) s += partial[(size_t)tg*22528 + i];
    out[i] = s * (1.0f/NT);
}

extern "C" void kernel_launch(void* const* d_in, const int* in_sizes, int n_in,
                              void* d_out, int out_size, void* d_ws, size_t ws_size,
                              hipStream_t stream)
{
    const float* x   = (const float*)d_in[0];
    const float* A   = (const float*)d_in[1];
    const float* g1  = (const float*)d_in[2];
    const float* bb1 = (const float*)d_in[3];
    const float* w1  = (const float*)d_in[4];
    const float* b1  = (const float*)d_in[5];
    const float* w2  = (const float*)d_in[6];
    const float* b2  = (const float*)d_in[7];
    const float* w3  = (const float*)d_in[8];
    const float* b3  = (const float*)d_in[9];
    const float* g2  = (const float*)d_in[10];
    const float* bb2 = (const float*)d_in[11];
    float* out = (float*)d_out;
    float* ws  = (float*)d_ws;
    unsigned short* xT  = (unsigned short*)((char*)d_ws + XT_BYTE);
    unsigned short* pws = (unsigned short*)((char*)d_ws + PWS_BYTE);
    float* part = (float*)((char*)d_ws + XT_BYTE);    // xT dead after k34

    hipMemsetAsync(d_ws, 0, 38400, stream);           // bn1/bn2 slots + params
    k0_tr  <<<2048, 256, 0, stream>>>(x, xT, ws);
    k2_fold<<<1,    256, 0, stream>>>(g1, bb1, w1, b1, w3, b3, ws);
    k34    <<<512,  256, 0, stream>>>(xT, A, w2, b2, w3, ws, pws);
    k5_fin <<<1,     64, 0, stream>>>(g2, bb2, ws);
    k6_acc <<<256,  256, 0, stream>>>(ws, pws, part);
    k6_out <<<88,   256, 0, stream>>>(part, out);
}

// Round 3
// 254.033 us; speedup vs baseline: 1.8838x; 1.8662x over previous
//
#include <hip/hip_runtime.h>
#include <hip/hip_fp16.h>

#define NB 2048
#define NC 8
#define NT 1024
#define EPS 1e-5f
#define SLOPE (1.0f/128.0f)
#define NELEM (2048.0f*1024.0f)

// ---- ws layout ----
// floats [0,1024)      : bn1 partials, 64 slots x 16
// floats [1024,9216)   : bn2 partials, 256 slots x 32
// floats [9216,9600)   : folded params
// byte 65536           : xT  fp16 [T][B][8]   (32 MiB)  (dead after k34 -> k6 partials)
// byte 65536+32MiB     : pre fp16 [t][b][12]  (48 MiB)
#define PAR_OFF 9216
#define P_S4  0      // 4*bn1_scale
#define P_O4  8      // 4*bn1_offset
#define P_W1F 16
#define P_B1F 208
#define P_W3X 232
#define P_B3F 320
#define P_AL  336
#define P_BE  352
#define P_A4  368    // 4*A, 64 floats
#define XT_BYTE  65536
#define PWS_BYTE (65536 + 2048*1024*8*2)

__device__ __forceinline__ float leaky(float z){ return fmaxf(z, z*SLOPE); }
__device__ __forceinline__ unsigned short f2h(float v){ return __half_as_ushort(__float2half(v)); }
__device__ __forceinline__ float h2f(unsigned short u){ return __half2float(__ushort_as_half(u)); }

// ---------------- K0: BN1 stats + transpose x -> xT[t][b][8] fp16 ----------------
__global__ __launch_bounds__(256) void k0_tr(const float* __restrict__ x,
                                             unsigned short* __restrict__ xT,
                                             float* __restrict__ ws)
{
    __shared__ unsigned short tile[64*134];
    __shared__ float sred[4][4][2];
    const int tid = threadIdx.x;
    const int bg = blockIdx.x >> 4;
    const int tg = blockIdx.x & 15;
    const int b0 = bg*16, t0 = tg*64;
    float s = 0.f, s2 = 0.f;
#pragma unroll
    for(int r=0;r<8;r++){
        const int flat4 = r*256 + tid;
        const int row = flat4 >> 4;          // 0..127 = b*8+c
        const int t4  = flat4 & 15;
        const int b = row >> 3, c = row & 7;
        float4 v = *(const float4*)(x + (size_t)(b0+b)*8192 + c*1024 + t0 + t4*4);
        s  += v.x+v.y+v.z+v.w;
        s2 += v.x*v.x+v.y*v.y+v.z*v.z+v.w*v.w;
        const int base = b*8 + c;
        tile[(t4*4+0)*134 + base] = f2h(v.x);
        tile[(t4*4+1)*134 + base] = f2h(v.y);
        tile[(t4*4+2)*134 + base] = f2h(v.z);
        tile[(t4*4+3)*134 + base] = f2h(v.w);
    }
    // per-thread c is constant: c=(tid>>4)&7; reduce within 16-lane groups
#pragma unroll
    for(int m=8;m>=1;m>>=1){ s += __shfl_xor(s,m,64); s2 += __shfl_xor(s2,m,64); }
    const int lane = tid & 63, wave = tid >> 6;
    if((lane & 15) == 0){ sred[wave][lane>>4][0] = s; sred[wave][lane>>4][1] = s2; }
    __syncthreads();
    if(tid < 16){
        const int c = tid & 7, which = tid >> 3;
        const int w0 = (c < 4) ? 0 : 1, g = c & 3;
        const float v = sred[w0][g][which] + sred[w0+2][g][which];
        atomicAdd(&ws[(blockIdx.x & 63)*16 + which*8 + c], v);
    }
#pragma unroll
    for(int r=0;r<8;r++){
        const int q = r*256 + tid;
        const int t = q >> 5, inner = q & 31;
        const unsigned int lo = *(const unsigned int*)&tile[t*134 + inner*4];
        const unsigned int hi = *(const unsigned int*)&tile[t*134 + inner*4 + 2];
        *(uint2*)(xT + ((size_t)(t0+t)*NB + b0)*8 + inner*4) = make_uint2(lo, hi);
    }
}

// ---------------- K2: finalize BN1, fold weights, prescale uniforms ----------------
__global__ __launch_bounds__(256) void k2_fold(const float* __restrict__ g1, const float* __restrict__ bb1,
    const float* __restrict__ w1, const float* __restrict__ b1,
    const float* __restrict__ w3, const float* __restrict__ b3,
    const float* __restrict__ A, float* __restrict__ ws)
{
    float* par = ws + PAR_OFF;
    __shared__ float st[16];
    __shared__ float sc[8], oc[8];
    const int tid = threadIdx.x;
    if(tid<16){
        float s=0.f;
        for(int i=0;i<64;i++) s += ws[i*16+tid];
        st[tid]=s;
    }
    __syncthreads();
    if(tid<8){
        const float inv = 1.0f/NELEM;
        float m  = st[tid]*inv;
        float v  = st[8+tid]*inv - m*m;
        float s_ = g1[tid]*rsqrtf(v+EPS);
        float o_ = bb1[tid] - m*s_;
        sc[tid]=s_; oc[tid]=o_;
        par[P_S4+tid]=4.f*s_; par[P_O4+tid]=4.f*o_;   // 4x folded here (k34 gets s_loads)
    }
    __syncthreads();
    if(tid<192){ int o=tid>>3, c=tid&7; par[P_W1F+tid] = w1[o*8+c]*sc[c]; }
    if(tid<88) { int o=tid>>3, c=tid&7; par[P_W3X+tid] = w3[o*48+c] + w3[o*48+8+c]*sc[c]; }
    if(tid<64) { par[P_A4+tid] = 4.f*A[tid]; }
    if(tid<24){ float a=b1[tid]; for(int c2=0;c2<8;c2++) a += w1[tid*8+c2]*oc[c2]; par[P_B1F+tid]=a; }
    if(tid<11){ float a=b3[tid]; for(int c2=0;c2<8;c2++) a += w3[tid*48+8+c2]*oc[c2]; par[P_B3F+tid]=a; }
}

// ---------------- K34: fused reservoir + FF + pre + BN2 partials ----------------
// grid: 8 bgroups(256 b) x 128 tgroups(8 t) = 1024 blocks x 256 thr -> 4 blocks/CU
// resident (launch_bounds caps VGPR at 128). Warm-up W=32: ||4A||_2 ~ 0.8 worst-case
// bound -> 0.8^32 ~ 8e-4; actual decay rho(4A)=0.4 -> ~1e-10. No f buffer.
__global__ __launch_bounds__(256,4) void k34(
    const unsigned short* __restrict__ xT,
    const float* __restrict__ w2g, const float* __restrict__ b2g, const float* __restrict__ w3g,
    float* __restrict__ ws, unsigned short* __restrict__ pws)
{
    const float* par = ws + PAR_OFF;
    const int tid = threadIdx.x;
    const int b  = (blockIdx.x >> 7)*256 + tid;
    const int tg = blockIdx.x & 127;
    const int t0 = tg*8;
    const int tw = (t0 >= 32) ? (t0 - 32) : 0;
    const int tend = t0 + 8;

    float f[8];
#pragma unroll
    for(int i=0;i<8;i++) f[i]=0.f;
    float s1[11], s2[11];
#pragma unroll
    for(int o=0;o<11;o++){ s1[o]=0.f; s2[o]=0.f; }

    for(int t=tw; t<tend; t++){
        union { float4 v; unsigned short us[8]; } ux;
        ux.v = *(const float4*)(xT + ((size_t)t*NB + b)*8);
        float xf[8];
#pragma unroll
        for(int i=0;i<8;i++) xf[i] = h2f(ux.us[i]);
        float nf[8];
#pragma unroll
        for(int i=0;i<8;i++){
            float acc = fmaf(par[P_S4+i], xf[i], par[P_O4+i]);   // 4*(s*x+o), SGPR operands
#pragma unroll
            for(int j=0;j<8;j++) acc = fmaf(par[P_A4+i*8+j], f[j], acc);
            nf[i] = fminf(fmaxf(acc,-1.f),1.f);                  // v_med3
        }
#pragma unroll
        for(int i=0;i<8;i++) f[i]=nf[i];
        if(t >= t0){                                              // uniform branch
            float h[24];
#pragma unroll
            for(int o=0;o<24;o++){
                float z = par[P_B1F+o];
#pragma unroll
                for(int c=0;c<8;c++) z = fmaf(par[P_W1F+o*8+c], xf[c], z);
                h[o]=leaky(z);
            }
            float ff[16];
#pragma unroll
            for(int o=0;o<16;o++){
                float z = b2g[o];
#pragma unroll
                for(int c=0;c<24;c++) z = fmaf(w2g[o*24+c], h[c], z);
                ff[o]=leaky(z);
            }
            float lf[8];
#pragma unroll
            for(int i=0;i<8;i++) lf[i] = leaky(f[i]);
            union { unsigned short us[12]; uint2 u[3]; } up;
#pragma unroll
            for(int o=0;o<11;o++){                                // one z live at a time
                float z = par[P_B3F+o];
#pragma unroll
                for(int c=0;c<8;c++) z = fmaf(par[P_W3X+o*8+c], xf[c], z);
#pragma unroll
                for(int i=0;i<8;i++) z = fmaf(w3g[o*48+32+i], f[i], z);
#pragma unroll
                for(int i=0;i<8;i++) z = fmaf(w3g[o*48+40+i], lf[i], z);
#pragma unroll
                for(int c=0;c<16;c++) z = fmaf(w3g[o*48+16+c], ff[c], z);
                s1[o]+=z; s2[o]+=z*z;
                up.us[o]=f2h(z);
            }
            up.us[11] = 0;
            uint2* dst = (uint2*)(pws + ((size_t)t*NB + b)*12);   // lanes on b: contiguous
            dst[0]=up.u[0]; dst[1]=up.u[1]; dst[2]=up.u[2];
        }
    }
    // BN2 partial reduction
#pragma unroll
    for(int o=0;o<11;o++){
#pragma unroll
        for(int m=32;m>=1;m>>=1){ s1[o]+=__shfl_xor(s1[o],m,64); s2[o]+=__shfl_xor(s2[o],m,64); }
    }
    __shared__ float red[4][22];
    const int wave=tid>>6, lane=tid&63;
    if(lane==0){
#pragma unroll
        for(int o=0;o<11;o++){ red[wave][o]=s1[o]; red[wave][11+o]=s2[o]; }
    }
    __syncthreads();
    if(tid<22){
        float tot = red[0][tid]+red[1][tid]+red[2][tid]+red[3][tid];
        atomicAdd(&ws[1024 + (blockIdx.x & 255)*32 + tid], tot);
    }
}

// ---------------- K5: finalize BN2 ----------------
__global__ __launch_bounds__(64) void k5_fin(const float* __restrict__ g2, const float* __restrict__ bb2,
                                             float* __restrict__ ws)
{
    __shared__ float st[22];
    const int tid = threadIdx.x;
    if(tid<22){
        float s=0.f;
        for(int i=0;i<256;i++) s += ws[1024 + i*32 + tid];
        st[tid]=s;
    }
    __syncthreads();
    if(tid<11){
        const float inv = 1.0f/NELEM;
        float m = st[tid]*inv;
        float v = st[11+tid]*inv - m*m;
        float a = g2[tid]*rsqrtf(v+EPS);
        ws[PAR_OFF+P_AL+tid] = a;
        ws[PAR_OFF+P_BE+tid] = bb2[tid] - m*a;
    }
}

// ---------------- K6a: BN2 apply + leaky + partial t-sums ----------------
__global__ __launch_bounds__(256) void k6_acc(const float* __restrict__ ws,
                                              const unsigned short* __restrict__ pws,
                                              float* __restrict__ partial)
{
    const float* par = ws + PAR_OFF;
    float al[11], be[11];
#pragma unroll
    for(int o=0;o<11;o++){ al[o]=par[P_AL+o]; be[o]=par[P_BE+o]; }
    const int tid = threadIdx.x;
    const int b  = (blockIdx.x >> 5)*256 + tid;
    const int tg = blockIdx.x & 31;
    float acc[11];
#pragma unroll
    for(int o=0;o<11;o++) acc[o]=0.f;
    for(int i=0;i<32;i++){
        const int t = tg*32 + i;
        const uint2* sp = (const uint2*)(pws + ((size_t)t*NB + b)*12);
        union { unsigned short us[12]; uint2 u[3]; } up;
        up.u[0]=sp[0]; up.u[1]=sp[1]; up.u[2]=sp[2];
#pragma unroll
        for(int o=0;o<11;o++) acc[o] += leaky(al[o]*h2f(up.us[o]) + be[o]);
    }
    float* dst = partial + ((size_t)tg*NB + b)*11;
#pragma unroll
    for(int o=0;o<11;o++) dst[o] = acc[o];
}

// ---------------- K6b: final mean ----------------
__global__ __launch_bounds__(256) void k6_out(const float* __restrict__ partial, float* __restrict__ out)
{
    const int i = blockIdx.x*256 + threadIdx.x;   // 88*256 = 22528 = 2048*11 exactly
    float s = 0.f;
    for(int tg=0; tg<32; tg++) s += partial[(size_t)tg*22528 + i];
    out[i] = s * (1.0f/NT);
}

extern "C" void kernel_launch(void* const* d_in, const int* in_sizes, int n_in,
                              void* d_out, int out_size, void* d_ws, size_t ws_size,
                              hipStream_t stream)
{
    const float* x   = (const float*)d_in[0];
    const float* A   = (const float*)d_in[1];
    const float* g1  = (const float*)d_in[2];
    const float* bb1 = (const float*)d_in[3];
    const float* w1  = (const float*)d_in[4];
    const float* b1  = (const float*)d_in[5];
    const float* w2  = (const float*)d_in[6];
    const float* b2  = (const float*)d_in[7];
    const float* w3  = (const float*)d_in[8];
    const float* b3  = (const float*)d_in[9];
    const float* g2  = (const float*)d_in[10];
    const float* bb2 = (const float*)d_in[11];
    float* out = (float*)d_out;
    float* ws  = (float*)d_ws;
    unsigned short* xT  = (unsigned short*)((char*)d_ws + XT_BYTE);
    unsigned short* pws = (unsigned short*)((char*)d_ws + PWS_BYTE);
    float* part = (float*)((char*)d_ws + XT_BYTE);    // xT dead after k34

    hipMemsetAsync(d_ws, 0, 38400, stream);           // bn1/bn2 slots + params
    k0_tr  <<<2048, 256, 0, stream>>>(x, xT, ws);
    k2_fold<<<1,    256, 0, stream>>>(g1, bb1, w1, b1, w3, b3, A, ws);
    k34    <<<1024, 256, 0, stream>>>(xT, w2, b2, w3, ws, pws);
    k5_fin <<<1,     64, 0, stream>>>(g2, bb2, ws);
    k6_acc <<<256,  256, 0, stream>>>(ws, pws, part);
    k6_out <<<88,   256, 0, stream>>>(part, out);
}

// Round 5
// 247.356 us; speedup vs baseline: 1.9347x; 1.0270x over previous
//
#include <hip/hip_runtime.h>
#include <hip/hip_fp16.h>

#define NB 2048
#define NC 8
#define NT 1024
#define EPS 1e-5f
#define SLOPE (1.0f/128.0f)
#define NELEM (2048.0f*1024.0f)
#define TB (NT*NB)

// ---- ws layout ----
// floats [0,1024)      : bn1 partials, 64 slots x 16
// floats [1024,9216)   : bn2 partials, 256 slots x 32
// floats [9216,10240)  : folded params (fp32 + packed-half2-as-uint)
// byte 65536           : xT  fp16 [T][B][8]     (32 MiB)
// byte 65536+32MiB     : pre fp16 [11][T][B]    (44 MiB planes)
#define PAR_OFF 9216
// fp32 (index into par float array)
#define PF_S4  0
#define PF_O4  8
#define PF_B1F 16
#define PF_B2F 40
#define PF_B3F 56
#define PF_AL  67
#define PF_BE  78
// packed half2 (index into (unsigned*)par)
#define PU_A4   96
#define PU_W1   128
#define PU_W2   224
#define PU_W3X  416
#define PU_W3F  460
#define PU_W3L  504
#define PU_W3FF 548
#define XT_BYTE  65536
#define PWS_BYTE (65536 + 2048*1024*8*2)

typedef _Float16 h2 __attribute__((ext_vector_type(2)));
typedef __fp16  fp16v2 __attribute__((ext_vector_type(2)));
union U32H2 { unsigned u; h2 h; fp16v2 f; unsigned short us[2]; };

__device__ __forceinline__ float leaky(float z){ return fmaxf(z, z*SLOPE); }
__device__ __forceinline__ unsigned short f2h(float v){ return __half_as_ushort(__float2half(v)); }
__device__ __forceinline__ float h2f(unsigned short u){ return __half2float(__ushort_as_half(u)); }
__device__ __forceinline__ h2 uph2(unsigned u){ U32H2 x; x.u = u; return x.h; }
__device__ __forceinline__ h2 pk(float a, float b){
    U32H2 x; x.f = __builtin_amdgcn_cvt_pkrtz(a, b); return x.h;   // v_cvt_pkrtz_f16_f32
}

#if defined(__has_builtin)
#if __has_builtin(__builtin_amdgcn_fdot2)
#define HAVE_FDOT2 1
#endif
#endif
#ifdef HAVE_FDOT2
__device__ __forceinline__ float fdot2(h2 a, h2 b, float c){ return __builtin_amdgcn_fdot2(a, b, c, false); }
#else
__device__ __forceinline__ float fdot2(h2 a, h2 b, float c){
    return c + (float)a[0]*(float)b[0] + (float)a[1]*(float)b[1];
}
#endif

// ---------------- K0: BN1 stats + transpose x -> xT[t][b][8] fp16 ----------------
__global__ __launch_bounds__(256) void k0_tr(const float* __restrict__ x,
                                             unsigned short* __restrict__ xT,
                                             float* __restrict__ ws)
{
    __shared__ unsigned short tile[64*134];
    __shared__ float sred[4][4][2];
    const int tid = threadIdx.x;
    const int bg = blockIdx.x >> 4;
    const int tg = blockIdx.x & 15;
    const int b0 = bg*16, t0 = tg*64;
    float s = 0.f, s2 = 0.f;
#pragma unroll
    for(int r=0;r<8;r++){
        const int flat4 = r*256 + tid;
        const int row = flat4 >> 4;          // 0..127 = b*8+c
        const int t4  = flat4 & 15;
        const int b = row >> 3, c = row & 7;
        float4 v = *(const float4*)(x + (size_t)(b0+b)*8192 + c*1024 + t0 + t4*4);
        s  += v.x+v.y+v.z+v.w;
        s2 += v.x*v.x+v.y*v.y+v.z*v.z+v.w*v.w;
        const int base = b*8 + c;
        tile[(t4*4+0)*134 + base] = f2h(v.x);
        tile[(t4*4+1)*134 + base] = f2h(v.y);
        tile[(t4*4+2)*134 + base] = f2h(v.z);
        tile[(t4*4+3)*134 + base] = f2h(v.w);
    }
    // per-thread c is constant within 16-lane groups
#pragma unroll
    for(int m=8;m>=1;m>>=1){ s += __shfl_xor(s,m,64); s2 += __shfl_xor(s2,m,64); }
    const int lane = tid & 63, wave = tid >> 6;
    if((lane & 15) == 0){ sred[wave][lane>>4][0] = s; sred[wave][lane>>4][1] = s2; }
    __syncthreads();
    if(tid < 16){
        const int c = tid & 7, which = tid >> 3;
        const int w0 = (c < 4) ? 0 : 1, g = c & 3;
        const float v = sred[w0][g][which] + sred[w0+2][g][which];
        atomicAdd(&ws[(blockIdx.x & 63)*16 + which*8 + c], v);
    }
#pragma unroll
    for(int r=0;r<8;r++){
        const int q = r*256 + tid;
        const int t = q >> 5, inner = q & 31;
        const unsigned int lo = *(const unsigned int*)&tile[t*134 + inner*4];
        const unsigned int hi = *(const unsigned int*)&tile[t*134 + inner*4 + 2];
        *(uint2*)(xT + ((size_t)(t0+t)*NB + b0)*8 + inner*4) = make_uint2(lo, hi);
    }
}

// ---------------- K2: finalize BN1, fold + pack all weights ----------------
__device__ __forceinline__ unsigned pk2u(float a, float b){
    U32H2 v; v.us[0] = f2h(a); v.us[1] = f2h(b); return v.u;
}
__global__ __launch_bounds__(256) void k2_fold(const float* __restrict__ g1, const float* __restrict__ bb1,
    const float* __restrict__ w1, const float* __restrict__ b1,
    const float* __restrict__ w2, const float* __restrict__ b2,
    const float* __restrict__ w3, const float* __restrict__ b3,
    const float* __restrict__ A, float* __restrict__ ws)
{
    float* par = ws + PAR_OFF;
    unsigned* paru = (unsigned*)par;
    __shared__ float st[16];
    __shared__ float sc[8], oc[8];
    const int tid = threadIdx.x;
    if(tid<16){
        float s=0.f;
        for(int i=0;i<64;i++) s += ws[i*16+tid];
        st[tid]=s;
    }
    __syncthreads();
    if(tid<8){
        const float inv = 1.0f/NELEM;
        float m  = st[tid]*inv;
        float v  = st[8+tid]*inv - m*m;
        float s_ = g1[tid]*rsqrtf(v+EPS);
        float o_ = bb1[tid] - m*s_;
        sc[tid]=s_; oc[tid]=o_;
        par[PF_S4+tid]=4.f*s_; par[PF_O4+tid]=4.f*o_;
    }
    __syncthreads();
    if(tid<24){ float a=b1[tid]; for(int c=0;c<8;c++) a += w1[tid*8+c]*oc[c]; par[PF_B1F+tid]=a; }
    if(tid<16){ par[PF_B2F+tid]=b2[tid]; }
    if(tid<11){ float a=b3[tid]; for(int c=0;c<8;c++) a += w3[tid*48+8+c]*oc[c]; par[PF_B3F+tid]=a; }
    if(tid<96){ int o=tid>>2, j=tid&3;
        paru[PU_W1+tid] = pk2u(w1[o*8+2*j]*sc[2*j], w1[o*8+2*j+1]*sc[2*j+1]); }
    if(tid<192){ int o=tid/12, j=tid-o*12;
        paru[PU_W2+tid] = pk2u(w2[o*24+2*j], w2[o*24+2*j+1]); }
    if(tid<44){ int o=tid>>2, j=tid&3; int c0=2*j, c1=2*j+1;
        float xa = w3[o*48+c0] + w3[o*48+8+c0]*sc[c0];
        float xb = w3[o*48+c1] + w3[o*48+8+c1]*sc[c1];
        paru[PU_W3X+tid] = pk2u(xa, xb);
        paru[PU_W3F+tid] = pk2u(w3[o*48+32+c0], w3[o*48+32+c1]);
        paru[PU_W3L+tid] = pk2u(w3[o*48+40+c0], w3[o*48+40+c1]);
    }
    if(tid<88){ int o=tid>>3, j=tid&7;
        paru[PU_W3FF+tid] = pk2u(w3[o*48+16+2*j], w3[o*48+16+2*j+1]); }
    if(tid<32){ int i=tid>>2, j=tid&3;
        paru[PU_A4+tid] = pk2u(4.f*A[i*8+2*j], 4.f*A[i*8+2*j+1]); }
}

// ---------------- K34: fused reservoir + FF + pre + BN2 partials (fdot2) ----------------
// grid: 8 bgroups(256 b) x 128 tgroups(8 t) = 1024 blocks. Warm-up W=32
// (||4A||_2~0.8 worst-case -> 0.8^32 ~ 8e-4; actual rho(4A)=0.4 -> negligible).
// All dots in packed half2 with fp32 accumulation (v_dot2_f32_f16).
__global__ __launch_bounds__(256,4) void k34(
    const unsigned short* __restrict__ xT,
    float* __restrict__ ws, unsigned short* __restrict__ pws)
{
    const float* par = ws + PAR_OFF;
    const unsigned* pu = (const unsigned*)par;
    const int tid = threadIdx.x;
    const int b  = (blockIdx.x >> 7)*256 + tid;
    const int tg = blockIdx.x & 127;
    const int t0 = tg*8;
    const int tw = (t0 >= 32) ? (t0 - 32) : 0;
    const int tend = t0 + 8;

    h2 fh[4];
#pragma unroll
    for(int j=0;j<4;j++) fh[j] = pk(0.f, 0.f);
    float s1[11], s2[11];
#pragma unroll
    for(int o=0;o<11;o++){ s1[o]=0.f; s2[o]=0.f; }

    for(int t=tw; t<tend; t++){
        union { float4 v; unsigned u[4]; unsigned short us[8]; } ux;
        ux.v = *(const float4*)(xT + ((size_t)t*NB + b)*8);
        h2 xh[4];
#pragma unroll
        for(int j=0;j<4;j++) xh[j] = uph2(ux.u[j]);
        float nf[8];
#pragma unroll
        for(int i=0;i<8;i++){
            float acc = fmaf(par[PF_S4+i], h2f(ux.us[i]), par[PF_O4+i]);
#pragma unroll
            for(int j=0;j<4;j++) acc = fdot2(uph2(pu[PU_A4+i*4+j]), fh[j], acc);
            nf[i] = fminf(fmaxf(acc,-1.f),1.f);             // v_med3
        }
#pragma unroll
        for(int j=0;j<4;j++) fh[j] = pk(nf[2*j], nf[2*j+1]);
        if(t >= t0){                                         // uniform branch
            h2 lfh[4];
#pragma unroll
            for(int j=0;j<4;j++) lfh[j] = pk(leaky(nf[2*j]), leaky(nf[2*j+1]));
            h2 hh[12];
#pragma unroll
            for(int p=0;p<12;p++){
                float za = par[PF_B1F+2*p], zb = par[PF_B1F+2*p+1];
#pragma unroll
                for(int j=0;j<4;j++){
                    za = fdot2(uph2(pu[PU_W1+(2*p)*4+j]),   xh[j], za);
                    zb = fdot2(uph2(pu[PU_W1+(2*p+1)*4+j]), xh[j], zb);
                }
                hh[p] = pk(leaky(za), leaky(zb));
            }
            h2 ffh[8];
#pragma unroll
            for(int p=0;p<8;p++){
                float za = par[PF_B2F+2*p], zb = par[PF_B2F+2*p+1];
#pragma unroll
                for(int j=0;j<12;j++){
                    za = fdot2(uph2(pu[PU_W2+(2*p)*12+j]),   hh[j], za);
                    zb = fdot2(uph2(pu[PU_W2+(2*p+1)*12+j]), hh[j], zb);
                }
                ffh[p] = pk(leaky(za), leaky(zb));
            }
            const size_t base = (size_t)t*NB + b;
#pragma unroll
            for(int o=0;o<11;o++){
                float z = par[PF_B3F+o];
#pragma unroll
                for(int j=0;j<4;j++) z = fdot2(uph2(pu[PU_W3X+o*4+j]),  xh[j],  z);
#pragma unroll
                for(int j=0;j<4;j++) z = fdot2(uph2(pu[PU_W3F+o*4+j]),  fh[j],  z);
#pragma unroll
                for(int j=0;j<4;j++) z = fdot2(uph2(pu[PU_W3L+o*4+j]),  lfh[j], z);
#pragma unroll
                for(int j=0;j<8;j++) z = fdot2(uph2(pu[PU_W3FF+o*8+j]), ffh[j], z);
                s1[o] += z; s2[o] += z*z;
                pws[(size_t)o*TB + base] = f2h(z);           // per-o plane: 128B/wave coalesced
            }
        }
    }
    // BN2 partial reduction
#pragma unroll
    for(int o=0;o<11;o++){
#pragma unroll
        for(int m=32;m>=1;m>>=1){ s1[o]+=__shfl_xor(s1[o],m,64); s2[o]+=__shfl_xor(s2[o],m,64); }
    }
    __shared__ float red[4][22];
    const int wave=tid>>6, lane=tid&63;
    if(lane==0){
#pragma unroll
        for(int o=0;o<11;o++){ red[wave][o]=s1[o]; red[wave][11+o]=s2[o]; }
    }
    __syncthreads();
    if(tid<22){
        float tot = red[0][tid]+red[1][tid]+red[2][tid]+red[3][tid];
        atomicAdd(&ws[1024 + (blockIdx.x & 255)*32 + tid], tot);
    }
}

// ---------------- K5: finalize BN2 ----------------
__global__ __launch_bounds__(64) void k5_fin(const float* __restrict__ g2, const float* __restrict__ bb2,
                                             float* __restrict__ ws)
{
    __shared__ float st[22];
    const int tid = threadIdx.x;
    if(tid<22){
        float s=0.f;
        for(int i=0;i<256;i++) s += ws[1024 + i*32 + tid];
        st[tid]=s;
    }
    __syncthreads();
    if(tid<11){
        const float inv = 1.0f/NELEM;
        float m = st[tid]*inv;
        float v = st[11+tid]*inv - m*m;
        float a = g2[tid]*rsqrtf(v+EPS);
        ws[PAR_OFF+PF_AL+tid] = a;
        ws[PAR_OFF+PF_BE+tid] = bb2[tid] - m*a;
    }
}

// ---------------- K6: BN2 apply + leaky + t-mean, atomic into out ----------------
// grid: 11 o x 8 bg x 16 tg = 1408 blocks (~5.5/CU). Coalesced 2B/lane plane reads.
__global__ __launch_bounds__(256) void k6(const float* __restrict__ ws,
                                          const unsigned short* __restrict__ pws,
                                          float* __restrict__ out)
{
    const float* par = ws + PAR_OFF;
    const int o  = blockIdx.x >> 7;
    const int r  = blockIdx.x & 127;
    const int bg = r & 7, tg = r >> 3;
    const int b  = bg*256 + threadIdx.x;
    const float al = par[PF_AL+o], be = par[PF_BE+o];
    const unsigned short* pp = pws + (size_t)o*TB + b;
    float acc = 0.f;
#pragma unroll 4
    for(int i=0;i<64;i++){
        const int t = tg*64 + i;
        acc += leaky(fmaf(al, h2f(pp[(size_t)t*NB]), be));
    }
    atomicAdd(&out[b*11+o], acc*(1.0f/NT));
}

extern "C" void kernel_launch(void* const* d_in, const int* in_sizes, int n_in,
                              void* d_out, int out_size, void* d_ws, size_t ws_size,
                              hipStream_t stream)
{
    const float* x   = (const float*)d_in[0];
    const float* A   = (const float*)d_in[1];
    const float* g1  = (const float*)d_in[2];
    const float* bb1 = (const float*)d_in[3];
    const float* w1  = (const float*)d_in[4];
    const float* b1  = (const float*)d_in[5];
    const float* w2  = (const float*)d_in[6];
    const float* b2  = (const float*)d_in[7];
    const float* w3  = (const float*)d_in[8];
    const float* b3  = (const float*)d_in[9];
    const float* g2  = (const float*)d_in[10];
    const float* bb2 = (const float*)d_in[11];
    float* out = (float*)d_out;
    float* ws  = (float*)d_ws;
    unsigned short* xT  = (unsigned short*)((char*)d_ws + XT_BYTE);
    unsigned short* pws = (unsigned short*)((char*)d_ws + PWS_BYTE);

    (void)hipMemsetAsync(d_ws, 0, 40960, stream);                 // bn1/bn2 slots + params
    (void)hipMemsetAsync(d_out, 0, (size_t)out_size*4, stream);   // k6 accumulates atomically
    k0_tr  <<<2048, 256, 0, stream>>>(x, xT, ws);
    k2_fold<<<1,    256, 0, stream>>>(g1, bb1, w1, b1, w2, b2, w3, b3, A, ws);
    k34    <<<1024, 256, 0, stream>>>(xT, ws, pws);
    k5_fin <<<1,     64, 0, stream>>>(g2, bb2, ws);
    k6     <<<1408, 256, 0, stream>>>(ws, pws, out);
}